// Round 10
// baseline (304.122 us; speedup 1.0000x reference)
//
#include <hip/hip_runtime.h>
#include <hip/hip_bf16.h>
#include <cstdint>
#include <cstddef>

// LinearAttention fused pipeline for MI355X (gfx950).
//   x:(8,256,16384) f32, w_qkv:(768,256), w_out:(256,256), b_out:(256), gn_w/gn_b:(256)
// Pipeline:
//   k_init : w_qkv -> bf16, zero accumulators
//   k_qkv  : per block (1/CU): 8 chunks of 64 l. Head-per-wave: GEMM 96x64 per wave,
//            q-softmax + exp(k) + Z fully in-register (shuffle reductions),
//            q stored via wave-local LDS transpose (dense u32 stores),
//            ctx via per-wave LDS transpose + MFMA, ctx/Z atomics ONCE per block.
//   k_w2   : W2[b,o,hd] = sum_e w_out[o,he]*ctx[b,h,d,e]/Z[b,hd]  (bf16)
//   k_out  : y = W2_b @ q_b + b_out -> d_out (f32), per-batch sum/sumsq atomics
//   k_stats: mean/var -> scale/shift
//   k_norm : d_out = d_out*A[b,c] + B[b,c] in place (GroupNorm + gn_w/gn_b)
// NOTE: this is a byte-exact revert to the round-6 passing version (302 us).
// Rounds 7-9 (global-sourced B-fragments) all NaN'd; mechanism unexplained,
// so we re-anchor here before bisecting that path further.

#define NB 8
#define NC 256
#define NL 16384
#define NH 8
#define ND 32
#define NO3 768
#define CHUNKS 8

#define Q_SCALE 0.17677669529663687f
#define GN_EPS 1e-5f

using f32x4  = __attribute__((ext_vector_type(4))) float;
using bf16x8 = __attribute__((ext_vector_type(8))) __bf16;
using u32x4  = __attribute__((ext_vector_type(4))) unsigned int;

__device__ __forceinline__ float bf2f(unsigned short u) {
    union { unsigned int i; float f; } v; v.i = ((unsigned int)u) << 16; return v.f;
}
__device__ __forceinline__ unsigned short f2bf(float f) {
    union { float f; unsigned int i; } v; v.f = f;
    v.i += 0x7fffu + ((v.i >> 16) & 1u);   // RNE
    return (unsigned short)(v.i >> 16);
}
__device__ __forceinline__ bf16x8 ldfrag(const unsigned short* p) {
    return __builtin_bit_cast(bf16x8, *(const u32x4*)p);
}

// ---------------------------------------------------------------- init
__global__ __launch_bounds__(256) void k_init(
    const float* __restrict__ wqkv, unsigned short* __restrict__ wq,
    float* __restrict__ ctx, float* __restrict__ Zs, float* __restrict__ stats)
{
    const int i0 = blockIdx.x * 256 + threadIdx.x;
    const int stride = gridDim.x * 256;
    for (int i = i0; i < NO3 * NC; i += stride) wq[i] = f2bf(wqkv[i]);
    for (int i = i0; i < NB * NH * ND * ND; i += stride) ctx[i] = 0.f;
    for (int i = i0; i < NB * NC; i += stride) Zs[i] = 0.f;
    if (i0 < 16) stats[i0] = 0.f;
}

// ---------------------------------------------------------------- pass 1
// grid (NL/(64*CHUNKS)=32, NB), 512 threads (8 waves). Wave w = head w.
__global__ __launch_bounds__(512, 2) void k_qkv(
    const float* __restrict__ x, const unsigned short* __restrict__ wq,
    unsigned short* __restrict__ q_ws, float* __restrict__ ctx, float* __restrict__ Zs)
{
    __shared__ __align__(16) unsigned short xT[2][64 * 256];    // 2x32 KB, swizzled [l][c]
    __shared__ __align__(16) unsigned short ekv[8][2][32 * 72]; // per-wave ek|v, 72 KB

    const int b    = blockIdx.y;
    const int lb   = blockIdx.x * (64 * CHUNKS);
    const int tid  = threadIdx.x;
    const int lane = tid & 63;
    const int w    = tid >> 6;          // wave id == head id
    const int m    = lane & 15;
    const int g    = lane >> 4;

    const float* xb = x + ((size_t)b << 22);   // x[b]

    f32x4 ca[2][2];                              // ctx accumulator (persist over chunks)
    #pragma unroll
    for (int i = 0; i < 2; ++i) {
        #pragma unroll
        for (int j = 0; j < 2; ++j) ca[i][j] = f32x4{0.f, 0.f, 0.f, 0.f};
    }
    float zacc[8] = {0.f,0.f,0.f,0.f,0.f,0.f,0.f,0.f};  // Z partials (rt',r)

    // prologue: stage chunk 0 into xT[0]
    {
        #pragma unroll
        for (int p = 0; p < 16; ++p) {
            const int cp = w + (p << 3);
            const float v0 = xb[((size_t)(2 * cp)     << 14) + lb + lane];
            const float v1 = xb[((size_t)(2 * cp + 1) << 14) + lb + lane];
            const unsigned int pk =
                (unsigned int)f2bf(v0) | ((unsigned int)f2bf(v1) << 16);
            *(unsigned int*)&xT[0][(((lane) << 8) + 2 * cp) ^ ((lane & 7) << 3)] = pk;
        }
    }
    __syncthreads();

    for (int t = 0; t < CHUNKS; ++t) {
        const int l0 = lb + (t << 6);
        const unsigned short* xcur = xT[t & 1];
        const bool pf = (t + 1 < CHUNKS);

        // launder wq so the 48 A-fragment loads can't be LICM-hoisted out of the
        // chunk loop (that would need 192 VGPRs of loop-carried fragments -> spill)
        uintptr_t wqa = (uintptr_t)wq;
        asm volatile("" : "+s"(wqa));
        const unsigned short* wqp = (const unsigned short*)wqa;

        // T14 split: issue next chunk's global loads NOW, ds_write after compute
        float sv0[16], sv1[16];
        if (pf) {
            #pragma unroll
            for (int p = 0; p < 16; ++p) {
                const int cp = w + (p << 3);
                sv0[p] = xb[((size_t)(2 * cp)     << 14) + l0 + 64 + lane];
                sv1[p] = xb[((size_t)(2 * cp + 1) << 14) + l0 + 64 + lane];
            }
        }

        // GEMM: this head's 96 rows x 64 cols, K=256
        f32x4 acc[6][4];
        #pragma unroll
        for (int i = 0; i < 6; ++i) {
            #pragma unroll
            for (int j = 0; j < 4; ++j) acc[i][j] = f32x4{0.f, 0.f, 0.f, 0.f};
        }
        #pragma unroll
        for (int ks = 0; ks < 8; ++ks) {
            bf16x8 afr[6], bfr[4];
            #pragma unroll
            for (int rt = 0; rt < 6; ++rt) {
                const int rb = ((rt >> 1) << 8) + 32 * w + ((rt & 1) << 4);
                afr[rt] = ldfrag(wqp + ((size_t)(rb + m) << 8) + (ks << 5) + (g << 3));
            }
            #pragma unroll
            for (int ct = 0; ct < 4; ++ct)
                bfr[ct] = ldfrag(&xcur[(((((ct << 4) + m) << 8) + (ks << 5) + (g << 3))
                                        ^ ((m & 7) << 3))]);
            #pragma unroll
            for (int rt = 0; rt < 6; ++rt) {
                #pragma unroll
                for (int ct = 0; ct < 4; ++ct)
                    acc[rt][ct] = __builtin_amdgcn_mfma_f32_16x16x32_bf16(
                        afr[rt], bfr[ct], acc[rt][ct], 0, 0, 0);
            }
        }

        // q softmax over d (in-register, g-group shuffle reduce)
        float rs[4];
        #pragma unroll
        for (int ct = 0; ct < 4; ++ct) {
            float s = 0.f;
            #pragma unroll
            for (int rt = 0; rt < 2; ++rt) {
                #pragma unroll
                for (int r = 0; r < 4; ++r) {
                    const float e = __expf(acc[rt][ct][r]);
                    acc[rt][ct][r] = e; s += e;
                }
            }
            s += __shfl_xor(s, 16);
            s += __shfl_xor(s, 32);
            rs[ct] = Q_SCALE / s;
        }

        unsigned short* eb = &ekv[w][0][0];
        unsigned short* vv = &ekv[w][1][0];

        // q -> wave-local LDS tile [d=32][l=64] (reusing eb), then dense u32 stores
        #pragma unroll
        for (int rt = 0; rt < 2; ++rt) {
            #pragma unroll
            for (int r = 0; r < 4; ++r) {
                const int dl = 16 * rt + 4 * g + r;
                #pragma unroll
                for (int ct = 0; ct < 4; ++ct)
                    eb[dl * 72 + (ct << 4) + m] = f2bf(acc[rt][ct][r] * rs[ct]);
            }
        }
        {
            unsigned short* qb = q_ws + ((size_t)(b * NC + 32 * w) << 14);
            const int half = lane >> 5, cu = lane & 31;
            #pragma unroll
            for (int i = 0; i < 16; ++i) {
                const int row = 2 * i + half;
                const unsigned int val = *(const unsigned int*)&eb[row * 72 + 2 * cu];
                *(unsigned int*)(qb + (((size_t)row << 14) + l0 + 2 * cu)) = val;
            }
        }

        // ek = exp(k) -> eb (overwrite, same-wave DS ops are in-order); v -> vv
        #pragma unroll
        for (int rt = 0; rt < 2; ++rt) {
            #pragma unroll
            for (int r = 0; r < 4; ++r) {
                const int dl = 16 * rt + 4 * g + r;
                #pragma unroll
                for (int ct = 0; ct < 4; ++ct) {
                    const unsigned short ue = f2bf(__expf(acc[2 + rt][ct][r]));
                    zacc[4 * rt + r] += bf2f(ue);   // sum rounded value (matches ctx)
                    eb[dl * 72 + (ct << 4) + m] = ue;
                    vv[dl * 72 + (ct << 4) + m] = f2bf(acc[4 + rt][ct][r]);
                }
            }
        }

        // ctx += ek @ v^T (wave-local LDS transpose read)
        #pragma unroll
        for (int ks = 0; ks < 2; ++ks) {
            const int co = (ks << 5) + (g << 3);
            bf16x8 ea0 = ldfrag(eb + m * 72 + co);
            bf16x8 ea1 = ldfrag(eb + (16 + m) * 72 + co);
            bf16x8 vb0 = ldfrag(vv + m * 72 + co);
            bf16x8 vb1 = ldfrag(vv + (16 + m) * 72 + co);
            ca[0][0] = __builtin_amdgcn_mfma_f32_16x16x32_bf16(ea0, vb0, ca[0][0], 0,0,0);
            ca[0][1] = __builtin_amdgcn_mfma_f32_16x16x32_bf16(ea0, vb1, ca[0][1], 0,0,0);
            ca[1][0] = __builtin_amdgcn_mfma_f32_16x16x32_bf16(ea1, vb0, ca[1][0], 0,0,0);
            ca[1][1] = __builtin_amdgcn_mfma_f32_16x16x32_bf16(ea1, vb1, ca[1][1], 0,0,0);
        }

        // finish staging: write prefetched chunk into the other buffer
        if (pf) {
            unsigned short* xn = xT[(t + 1) & 1];
            #pragma unroll
            for (int p = 0; p < 16; ++p) {
                const int cp = w + (p << 3);
                const unsigned int pk =
                    (unsigned int)f2bf(sv0[p]) | ((unsigned int)f2bf(sv1[p]) << 16);
                *(unsigned int*)&xn[(((lane) << 8) + 2 * cp) ^ ((lane & 7) << 3)] = pk;
            }
        }
        __syncthreads();
    }

    // epilogue: Z atomics (reduce over m within 16-group first)
    #pragma unroll
    for (int i = 0; i < 8; ++i) {
        float z = zacc[i];
        z += __shfl_xor(z, 1); z += __shfl_xor(z, 2);
        z += __shfl_xor(z, 4); z += __shfl_xor(z, 8);
        if (m == 0)
            atomicAdd(Zs + b * NC + 32 * w + ((i >> 2) << 4) + 4 * g + (i & 3), z);
    }
    // ctx atomics, once per block
    float* cb = ctx + ((size_t)(b * NH + w) << 10);
    #pragma unroll
    for (int mt = 0; mt < 2; ++mt) {
        #pragma unroll
        for (int nt = 0; nt < 2; ++nt) {
            #pragma unroll
            for (int r = 0; r < 4; ++r)
                atomicAdd(cb + (((mt << 4) + 4 * g + r) << 5) + (nt << 4) + m,
                          ca[mt][nt][r]);
        }
    }
}

// ---------------------------------------------------------------- W2 build
// grid (NC, NB), 256 threads. W2[b,o,c=(h*32+d)] = sum_e w_out[o,h*32+e]*ctx[b,h,d,e]/Z[b,c]
__global__ __launch_bounds__(256) void k_w2(
    const float* __restrict__ w_out, const float* __restrict__ ctx,
    const float* __restrict__ Zs, unsigned short* __restrict__ W2)
{
    const int b = blockIdx.y, o = blockIdx.x, c = threadIdx.x;
    const int h = c >> 5, d = c & 31;
    const float zinv = 1.f / Zs[b * NC + c];
    const float* wrow = w_out + (o << 8) + (h << 5);
    const float* crow = ctx + ((b * NH + h) << 10) + (d << 5);
    float s = 0.f;
    #pragma unroll
    for (int e = 0; e < 32; ++e) s += wrow[e] * crow[e];
    W2[((size_t)(b * NC + o) << 8) + c] = f2bf(s * zinv);
}

// ---------------------------------------------------------------- pass 2
// grid (NL/128, NB), 512 threads. y = W2_b @ q_b + b_out ; sum/sumsq atomics.
__global__ __launch_bounds__(512) void k_out(
    const unsigned short* __restrict__ q_ws, const unsigned short* __restrict__ W2,
    const float* __restrict__ b_out, float* __restrict__ y, float* __restrict__ stats)
{
    __shared__ __align__(16) unsigned short qT[128 * 256];  // [l][c] bf16, swizzled (64 KB)
    __shared__ float red[16];

    const int b    = blockIdx.y;
    const int l0   = blockIdx.x << 7;
    const int tid  = threadIdx.x;
    const int lane = tid & 63, w = tid >> 6, m = lane & 15, g = lane >> 4;

    // stage q^T tile (bf16 bits copied, no conversion)
    {
        const int l = tid & 127, c0 = tid >> 7;
        const unsigned short* qp = q_ws + ((size_t)b << 22) + l0 + l;
        #pragma unroll 16
        for (int p = 0; p < 64; ++p) {
            const int c = c0 + (p << 2);
            qT[(l * 256 + c) ^ ((l & 7) << 3)] = qp[(size_t)c << 14];
        }
    }
    __syncthreads();

    const unsigned short* W2b = W2 + ((size_t)b << 16);
    f32x4 acc[2][8];
    #pragma unroll
    for (int i = 0; i < 2; ++i) {
        #pragma unroll
        for (int j = 0; j < 8; ++j) acc[i][j] = f32x4{0.f, 0.f, 0.f, 0.f};
    }
    #pragma unroll
    for (int ks = 0; ks < 8; ++ks) {
        bf16x8 afr[2], bfr[8];
        #pragma unroll
        for (int rt = 0; rt < 2; ++rt)
            afr[rt] = ldfrag(W2b + ((32 * w + 16 * rt + m) << 8) + (ks << 5) + (g << 3));
        #pragma unroll
        for (int ct = 0; ct < 8; ++ct) {
            const int col = (ct << 4) + m;
            bfr[ct] = ldfrag(qT + ((col * 256 + (ks << 5) + (g << 3)) ^ ((col & 7) << 3)));
        }
        #pragma unroll
        for (int rt = 0; rt < 2; ++rt) {
            #pragma unroll
            for (int ct = 0; ct < 8; ++ct)
                acc[rt][ct] = __builtin_amdgcn_mfma_f32_16x16x32_bf16(
                    afr[rt], bfr[ct], acc[rt][ct], 0, 0, 0);
        }
    }

    // epilogue: +b_out, write y, per-batch sum/sumsq
    float lsum = 0.f, lsq = 0.f;
    #pragma unroll
    for (int rt = 0; rt < 2; ++rt) {
        #pragma unroll
        for (int r = 0; r < 4; ++r) {
            const int row = 32 * w + 16 * rt + 4 * g + r;
            const float bo = b_out[row];
            float* yp = y + ((size_t)(b * NC + row) << 14) + l0 + m;
            #pragma unroll
            for (int ct = 0; ct < 8; ++ct) {
                const float v = acc[rt][ct][r] + bo;
                yp[ct << 4] = v;
                lsum += v; lsq += v * v;
            }
        }
    }
    #pragma unroll
    for (int off = 32; off > 0; off >>= 1) {
        lsum += __shfl_xor(lsum, off);
        lsq  += __shfl_xor(lsq,  off);
    }
    if (lane == 0) { red[w] = lsum; red[8 + w] = lsq; }
    __syncthreads();
    if (tid == 0) {
        float s = 0.f, s2 = 0.f;
        #pragma unroll
        for (int i = 0; i < 8; ++i) { s += red[i]; s2 += red[8 + i]; }
        atomicAdd(stats + b, s);
        atomicAdd(stats + 8 + b, s2);
    }
}

// ---------------------------------------------------------------- stats
__global__ __launch_bounds__(64) void k_stats(const float* __restrict__ stats,
                                              float* __restrict__ sc)
{
    const int b = threadIdx.x;
    if (b < 8) {
        const float invN = 1.f / 4194304.f;  // C*L
        const float mean = stats[b] * invN;
        const float var  = stats[8 + b] * invN - mean * mean;
        const float inv  = rsqrtf(var + GN_EPS);
        sc[b] = inv;
        sc[8 + b] = -mean * inv;
    }
}

// ---------------------------------------------------------------- normalize (in place)
__global__ __launch_bounds__(256) void k_norm(float* __restrict__ y,
    const float* __restrict__ sc, const float* __restrict__ gw, const float* __restrict__ gb)
{
    const size_t n4 = (size_t)NB * NC * NL / 4;
    for (size_t i = (size_t)blockIdx.x * 256 + threadIdx.x; i < n4;
         i += (size_t)gridDim.x * 256) {
        const size_t idx = i << 2;
        const int b = (int)(idx >> 22);
        const int c = (int)(idx >> 14) & 255;
        float4 v = ((float4*)y)[i];
        const float A  = sc[b] * gw[c];
        const float Bc = sc[8 + b] * gw[c] + gb[c];
        v.x = v.x * A + Bc; v.y = v.y * A + Bc;
        v.z = v.z * A + Bc; v.w = v.w * A + Bc;
        ((float4*)y)[i] = v;
    }
}

// ---------------------------------------------------------------- launcher
extern "C" void kernel_launch(void* const* d_in, const int* in_sizes, int n_in,
                              void* d_out, int out_size, void* d_ws, size_t ws_size,
                              hipStream_t stream)
{
    (void)in_sizes; (void)n_in; (void)out_size; (void)ws_size;
    const float* x     = (const float*)d_in[0];
    const float* w_qkv = (const float*)d_in[1];
    const float* w_out = (const float*)d_in[2];
    const float* b_out = (const float*)d_in[3];
    const float* gn_w  = (const float*)d_in[4];
    const float* gn_b  = (const float*)d_in[5];
    float* out = (float*)d_out;

    char* ws = (char*)d_ws;
    unsigned short* q_ws = (unsigned short*)(ws);              // 67,108,864 B
    unsigned short* wq   = (unsigned short*)(ws + 67108864);   //    393,216 B
    unsigned short* W2   = (unsigned short*)(ws + 67502080);   //  1,048,576 B
    float* ctx   = (float*)(ws + 68550656);                    //    262,144 B
    float* Zs    = (float*)(ws + 68812800);                    //      8,192 B
    float* stats = (float*)(ws + 68820992);                    //         64 B
    float* sc    = (float*)(ws + 68821056);                    //         64 B

    k_init <<<dim3(256),                    dim3(256), 0, stream>>>(w_qkv, wq, ctx, Zs, stats);
    k_qkv  <<<dim3(NL / (64 * CHUNKS), NB), dim3(512), 0, stream>>>(x, wq, q_ws, ctx, Zs);
    k_w2   <<<dim3(NC, NB),                 dim3(256), 0, stream>>>(w_out, ctx, Zs, W2);
    k_out  <<<dim3(NL / 128, NB),           dim3(512), 0, stream>>>(q_ws, W2, b_out, out, stats);
    k_stats<<<dim3(1),                      dim3(64),  0, stream>>>(stats, sc);
    k_norm <<<dim3(2048),                   dim3(256), 0, stream>>>(out, sc, gn_w, gn_b);
}

// Round 12
// 294.749 us; speedup vs baseline: 1.0318x; 1.0318x over previous
//
#include <hip/hip_runtime.h>
#include <hip/hip_bf16.h>
#include <cstdint>
#include <cstddef>

// LinearAttention fused pipeline for MI355X (gfx950).
//   x:(8,256,16384) f32, w_qkv:(768,256), w_out:(256,256), b_out:(256), gn_w/gn_b:(256)
// Pipeline:
//   k_init : w_qkv -> bf16, zero accumulators
//   k_qkv  : (r6/r10-proven, FROZEN) per block: 8 chunks of 64 l, head-per-wave,
//            in-register softmax/exp/Z, wave-local LDS transposes, ctx/Z atomics.
//   k_w2   : W2[b,o,hd] = sum_e w_out[o,he]*ctx[b,h,d,e]/Z[b,hd]  (bf16)
//   k_out  : y = W2_b @ q_b + b_out -> bf16, IN-PLACE into q_ws (each block's
//            q window is dead after its qT staging barrier); f32 sum/sumsq atomics.
//   k_stats: mean/var -> scale/shift
//   k_norm : d_out = bf2f(y_bf)*A[b,c] + B[b,c]  (GroupNorm + gn_w/gn_b), f32 out.

#define NB 8
#define NC 256
#define NL 16384
#define NH 8
#define ND 32
#define NO3 768
#define CHUNKS 8

#define Q_SCALE 0.17677669529663687f
#define GN_EPS 1e-5f

using f32x4  = __attribute__((ext_vector_type(4))) float;
using bf16x8 = __attribute__((ext_vector_type(8))) __bf16;
using u32x4  = __attribute__((ext_vector_type(4))) unsigned int;

__device__ __forceinline__ float bf2f(unsigned short u) {
    union { unsigned int i; float f; } v; v.i = ((unsigned int)u) << 16; return v.f;
}
__device__ __forceinline__ unsigned short f2bf(float f) {
    union { float f; unsigned int i; } v; v.f = f;
    v.i += 0x7fffu + ((v.i >> 16) & 1u);   // RNE
    return (unsigned short)(v.i >> 16);
}
__device__ __forceinline__ bf16x8 ldfrag(const unsigned short* p) {
    return __builtin_bit_cast(bf16x8, *(const u32x4*)p);
}

// ---------------------------------------------------------------- init
__global__ __launch_bounds__(256) void k_init(
    const float* __restrict__ wqkv, unsigned short* __restrict__ wq,
    float* __restrict__ ctx, float* __restrict__ Zs, float* __restrict__ stats)
{
    const int i0 = blockIdx.x * 256 + threadIdx.x;
    const int stride = gridDim.x * 256;
    for (int i = i0; i < NO3 * NC; i += stride) wq[i] = f2bf(wqkv[i]);
    for (int i = i0; i < NB * NH * ND * ND; i += stride) ctx[i] = 0.f;
    for (int i = i0; i < NB * NC; i += stride) Zs[i] = 0.f;
    if (i0 < 16) stats[i0] = 0.f;
}

// ---------------------------------------------------------------- pass 1
// grid (NL/(64*CHUNKS)=32, NB), 512 threads (8 waves). Wave w = head w.
// FROZEN: byte-identical to the round-6/round-10 passing version.
__global__ __launch_bounds__(512, 2) void k_qkv(
    const float* __restrict__ x, const unsigned short* __restrict__ wq,
    unsigned short* __restrict__ q_ws, float* __restrict__ ctx, float* __restrict__ Zs)
{
    __shared__ __align__(16) unsigned short xT[2][64 * 256];    // 2x32 KB, swizzled [l][c]
    __shared__ __align__(16) unsigned short ekv[8][2][32 * 72]; // per-wave ek|v, 72 KB

    const int b    = blockIdx.y;
    const int lb   = blockIdx.x * (64 * CHUNKS);
    const int tid  = threadIdx.x;
    const int lane = tid & 63;
    const int w    = tid >> 6;          // wave id == head id
    const int m    = lane & 15;
    const int g    = lane >> 4;

    const float* xb = x + ((size_t)b << 22);   // x[b]

    f32x4 ca[2][2];                              // ctx accumulator (persist over chunks)
    #pragma unroll
    for (int i = 0; i < 2; ++i) {
        #pragma unroll
        for (int j = 0; j < 2; ++j) ca[i][j] = f32x4{0.f, 0.f, 0.f, 0.f};
    }
    float zacc[8] = {0.f,0.f,0.f,0.f,0.f,0.f,0.f,0.f};  // Z partials (rt',r)

    // prologue: stage chunk 0 into xT[0]
    {
        #pragma unroll
        for (int p = 0; p < 16; ++p) {
            const int cp = w + (p << 3);
            const float v0 = xb[((size_t)(2 * cp)     << 14) + lb + lane];
            const float v1 = xb[((size_t)(2 * cp + 1) << 14) + lb + lane];
            const unsigned int pk =
                (unsigned int)f2bf(v0) | ((unsigned int)f2bf(v1) << 16);
            *(unsigned int*)&xT[0][(((lane) << 8) + 2 * cp) ^ ((lane & 7) << 3)] = pk;
        }
    }
    __syncthreads();

    for (int t = 0; t < CHUNKS; ++t) {
        const int l0 = lb + (t << 6);
        const unsigned short* xcur = xT[t & 1];
        const bool pf = (t + 1 < CHUNKS);

        // launder wq so the 48 A-fragment loads can't be LICM-hoisted out of the
        // chunk loop (that would need 192 VGPRs of loop-carried fragments -> spill)
        uintptr_t wqa = (uintptr_t)wq;
        asm volatile("" : "+s"(wqa));
        const unsigned short* wqp = (const unsigned short*)wqa;

        // T14 split: issue next chunk's global loads NOW, ds_write after compute
        float sv0[16], sv1[16];
        if (pf) {
            #pragma unroll
            for (int p = 0; p < 16; ++p) {
                const int cp = w + (p << 3);
                sv0[p] = xb[((size_t)(2 * cp)     << 14) + l0 + 64 + lane];
                sv1[p] = xb[((size_t)(2 * cp + 1) << 14) + l0 + 64 + lane];
            }
        }

        // GEMM: this head's 96 rows x 64 cols, K=256
        f32x4 acc[6][4];
        #pragma unroll
        for (int i = 0; i < 6; ++i) {
            #pragma unroll
            for (int j = 0; j < 4; ++j) acc[i][j] = f32x4{0.f, 0.f, 0.f, 0.f};
        }
        #pragma unroll
        for (int ks = 0; ks < 8; ++ks) {
            bf16x8 afr[6], bfr[4];
            #pragma unroll
            for (int rt = 0; rt < 6; ++rt) {
                const int rb = ((rt >> 1) << 8) + 32 * w + ((rt & 1) << 4);
                afr[rt] = ldfrag(wqp + ((size_t)(rb + m) << 8) + (ks << 5) + (g << 3));
            }
            #pragma unroll
            for (int ct = 0; ct < 4; ++ct)
                bfr[ct] = ldfrag(&xcur[(((((ct << 4) + m) << 8) + (ks << 5) + (g << 3))
                                        ^ ((m & 7) << 3))]);
            #pragma unroll
            for (int rt = 0; rt < 6; ++rt) {
                #pragma unroll
                for (int ct = 0; ct < 4; ++ct)
                    acc[rt][ct] = __builtin_amdgcn_mfma_f32_16x16x32_bf16(
                        afr[rt], bfr[ct], acc[rt][ct], 0, 0, 0);
            }
        }

        // q softmax over d (in-register, g-group shuffle reduce)
        float rs[4];
        #pragma unroll
        for (int ct = 0; ct < 4; ++ct) {
            float s = 0.f;
            #pragma unroll
            for (int rt = 0; rt < 2; ++rt) {
                #pragma unroll
                for (int r = 0; r < 4; ++r) {
                    const float e = __expf(acc[rt][ct][r]);
                    acc[rt][ct][r] = e; s += e;
                }
            }
            s += __shfl_xor(s, 16);
            s += __shfl_xor(s, 32);
            rs[ct] = Q_SCALE / s;
        }

        unsigned short* eb = &ekv[w][0][0];
        unsigned short* vv = &ekv[w][1][0];

        // q -> wave-local LDS tile [d=32][l=64] (reusing eb), then dense u32 stores
        #pragma unroll
        for (int rt = 0; rt < 2; ++rt) {
            #pragma unroll
            for (int r = 0; r < 4; ++r) {
                const int dl = 16 * rt + 4 * g + r;
                #pragma unroll
                for (int ct = 0; ct < 4; ++ct)
                    eb[dl * 72 + (ct << 4) + m] = f2bf(acc[rt][ct][r] * rs[ct]);
            }
        }
        {
            unsigned short* qb = q_ws + ((size_t)(b * NC + 32 * w) << 14);
            const int half = lane >> 5, cu = lane & 31;
            #pragma unroll
            for (int i = 0; i < 16; ++i) {
                const int row = 2 * i + half;
                const unsigned int val = *(const unsigned int*)&eb[row * 72 + 2 * cu];
                *(unsigned int*)(qb + (((size_t)row << 14) + l0 + 2 * cu)) = val;
            }
        }

        // ek = exp(k) -> eb (overwrite, same-wave DS ops are in-order); v -> vv
        #pragma unroll
        for (int rt = 0; rt < 2; ++rt) {
            #pragma unroll
            for (int r = 0; r < 4; ++r) {
                const int dl = 16 * rt + 4 * g + r;
                #pragma unroll
                for (int ct = 0; ct < 4; ++ct) {
                    const unsigned short ue = f2bf(__expf(acc[2 + rt][ct][r]));
                    zacc[4 * rt + r] += bf2f(ue);   // sum rounded value (matches ctx)
                    eb[dl * 72 + (ct << 4) + m] = ue;
                    vv[dl * 72 + (ct << 4) + m] = f2bf(acc[4 + rt][ct][r]);
                }
            }
        }

        // ctx += ek @ v^T (wave-local LDS transpose read)
        #pragma unroll
        for (int ks = 0; ks < 2; ++ks) {
            const int co = (ks << 5) + (g << 3);
            bf16x8 ea0 = ldfrag(eb + m * 72 + co);
            bf16x8 ea1 = ldfrag(eb + (16 + m) * 72 + co);
            bf16x8 vb0 = ldfrag(vv + m * 72 + co);
            bf16x8 vb1 = ldfrag(vv + (16 + m) * 72 + co);
            ca[0][0] = __builtin_amdgcn_mfma_f32_16x16x32_bf16(ea0, vb0, ca[0][0], 0,0,0);
            ca[0][1] = __builtin_amdgcn_mfma_f32_16x16x32_bf16(ea0, vb1, ca[0][1], 0,0,0);
            ca[1][0] = __builtin_amdgcn_mfma_f32_16x16x32_bf16(ea1, vb0, ca[1][0], 0,0,0);
            ca[1][1] = __builtin_amdgcn_mfma_f32_16x16x32_bf16(ea1, vb1, ca[1][1], 0,0,0);
        }

        // finish staging: write prefetched chunk into the other buffer
        if (pf) {
            unsigned short* xn = xT[(t + 1) & 1];
            #pragma unroll
            for (int p = 0; p < 16; ++p) {
                const int cp = w + (p << 3);
                const unsigned int pk =
                    (unsigned int)f2bf(sv0[p]) | ((unsigned int)f2bf(sv1[p]) << 16);
                *(unsigned int*)&xn[(((lane) << 8) + 2 * cp) ^ ((lane & 7) << 3)] = pk;
            }
        }
        __syncthreads();
    }

    // epilogue: Z atomics (reduce over m within 16-group first)
    #pragma unroll
    for (int i = 0; i < 8; ++i) {
        float z = zacc[i];
        z += __shfl_xor(z, 1); z += __shfl_xor(z, 2);
        z += __shfl_xor(z, 4); z += __shfl_xor(z, 8);
        if (m == 0)
            atomicAdd(Zs + b * NC + 32 * w + ((i >> 2) << 4) + 4 * g + (i & 3), z);
    }
    // ctx atomics, once per block
    float* cb = ctx + ((size_t)(b * NH + w) << 10);
    #pragma unroll
    for (int mt = 0; mt < 2; ++mt) {
        #pragma unroll
        for (int nt = 0; nt < 2; ++nt) {
            #pragma unroll
            for (int r = 0; r < 4; ++r)
                atomicAdd(cb + (((mt << 4) + 4 * g + r) << 5) + (nt << 4) + m,
                          ca[mt][nt][r]);
        }
    }
}

// ---------------------------------------------------------------- W2 build
// grid (NC, NB), 256 threads. W2[b,o,c=(h*32+d)] = sum_e w_out[o,h*32+e]*ctx[b,h,d,e]/Z[b,c]
__global__ __launch_bounds__(256) void k_w2(
    const float* __restrict__ w_out, const float* __restrict__ ctx,
    const float* __restrict__ Zs, unsigned short* __restrict__ W2)
{
    const int b = blockIdx.y, o = blockIdx.x, c = threadIdx.x;
    const int h = c >> 5, d = c & 31;
    const float zinv = 1.f / Zs[b * NC + c];
    const float* wrow = w_out + (o << 8) + (h << 5);
    const float* crow = ctx + ((b * NH + h) << 10) + (d << 5);
    float s = 0.f;
    #pragma unroll
    for (int e = 0; e < 32; ++e) s += wrow[e] * crow[e];
    W2[((size_t)(b * NC + o) << 8) + c] = f2bf(s * zinv);
}

// ---------------------------------------------------------------- pass 2
// grid (NL/128, NB), 512 threads. y = W2_b @ q_b + b_out -> bf16 IN-PLACE into
// qy (the q_ws buffer: this block's q window [b][:, l0..l0+127] is dead after
// the qT staging barrier — no other block reads it). Per-batch sum/sumsq atomics
// computed from exact f32 values.
__global__ __launch_bounds__(512) void k_out(
    unsigned short* qy, const unsigned short* __restrict__ W2,
    const float* __restrict__ b_out, float* __restrict__ stats)
{
    __shared__ __align__(16) unsigned short qT[128 * 256];  // [l][c] bf16, swizzled (64 KB)
    __shared__ float red[16];

    const int b    = blockIdx.y;
    const int l0   = blockIdx.x << 7;
    const int tid  = threadIdx.x;
    const int lane = tid & 63, w = tid >> 6, m = lane & 15, g = lane >> 4;

    // stage q^T tile (bf16 bits copied, no conversion)
    {
        const int l = tid & 127, c0 = tid >> 7;
        const unsigned short* qp = qy + ((size_t)b << 22) + l0 + l;
        #pragma unroll 16
        for (int p = 0; p < 64; ++p) {
            const int c = c0 + (p << 2);
            qT[(l * 256 + c) ^ ((l & 7) << 3)] = qp[(size_t)c << 14];
        }
    }
    __syncthreads();

    const unsigned short* W2b = W2 + ((size_t)b << 16);
    f32x4 acc[2][8];
    #pragma unroll
    for (int i = 0; i < 2; ++i) {
        #pragma unroll
        for (int j = 0; j < 8; ++j) acc[i][j] = f32x4{0.f, 0.f, 0.f, 0.f};
    }
    #pragma unroll
    for (int ks = 0; ks < 8; ++ks) {
        bf16x8 afr[2], bfr[8];
        #pragma unroll
        for (int rt = 0; rt < 2; ++rt)
            afr[rt] = ldfrag(W2b + ((32 * w + 16 * rt + m) << 8) + (ks << 5) + (g << 3));
        #pragma unroll
        for (int ct = 0; ct < 8; ++ct) {
            const int col = (ct << 4) + m;
            bfr[ct] = ldfrag(qT + ((col * 256 + (ks << 5) + (g << 3)) ^ ((col & 7) << 3)));
        }
        #pragma unroll
        for (int rt = 0; rt < 2; ++rt) {
            #pragma unroll
            for (int ct = 0; ct < 8; ++ct)
                acc[rt][ct] = __builtin_amdgcn_mfma_f32_16x16x32_bf16(
                    afr[rt], bfr[ct], acc[rt][ct], 0, 0, 0);
        }
    }

    // epilogue: +b_out, write y as bf16 (in place), per-batch sum/sumsq (f32)
    float lsum = 0.f, lsq = 0.f;
    #pragma unroll
    for (int rt = 0; rt < 2; ++rt) {
        #pragma unroll
        for (int r = 0; r < 4; ++r) {
            const int row = 32 * w + 16 * rt + 4 * g + r;
            const float bo = b_out[row];
            unsigned short* yp = qy + ((size_t)(b * NC + row) << 14) + l0 + m;
            #pragma unroll
            for (int ct = 0; ct < 8; ++ct) {
                const float v = acc[rt][ct][r] + bo;
                yp[ct << 4] = f2bf(v);
                lsum += v; lsq += v * v;
            }
        }
    }
    #pragma unroll
    for (int off = 32; off > 0; off >>= 1) {
        lsum += __shfl_xor(lsum, off);
        lsq  += __shfl_xor(lsq,  off);
    }
    if (lane == 0) { red[w] = lsum; red[8 + w] = lsq; }
    __syncthreads();
    if (tid == 0) {
        float s = 0.f, s2 = 0.f;
        #pragma unroll
        for (int i = 0; i < 8; ++i) { s += red[i]; s2 += red[8 + i]; }
        atomicAdd(stats + b, s);
        atomicAdd(stats + 8 + b, s2);
    }
}

// ---------------------------------------------------------------- stats
__global__ __launch_bounds__(64) void k_stats(const float* __restrict__ stats,
                                              float* __restrict__ sc)
{
    const int b = threadIdx.x;
    if (b < 8) {
        const float invN = 1.f / 4194304.f;  // C*L
        const float mean = stats[b] * invN;
        const float var  = stats[8 + b] * invN - mean * mean;
        const float inv  = rsqrtf(var + GN_EPS);
        sc[b] = inv;
        sc[8 + b] = -mean * inv;
    }
}

// ---------------------------------------------------------------- normalize
// read y_bf (bf16, in q_ws memory), write final f32 out. 8 elements/thread.
__global__ __launch_bounds__(256) void k_norm(
    const unsigned short* __restrict__ ybf, float* __restrict__ y,
    const float* __restrict__ sc, const float* __restrict__ gw,
    const float* __restrict__ gb)
{
    const size_t n8 = (size_t)NB * NC * NL / 8;
    for (size_t i = (size_t)blockIdx.x * 256 + threadIdx.x; i < n8;
         i += (size_t)gridDim.x * 256) {
        const size_t idx = i << 3;
        const int b = (int)(idx >> 22);
        const int c = (int)((idx >> 14) & 255);
        const u32x4 v = *(const u32x4*)(ybf + idx);
        const float A  = sc[b] * gw[c];
        const float Bc = sc[8 + b] * gw[c] + gb[c];
        float4 o0, o1;
        o0.x = bf2f((unsigned short)(v[0] & 0xffffu)) * A + Bc;
        o0.y = bf2f((unsigned short)(v[0] >> 16))     * A + Bc;
        o0.z = bf2f((unsigned short)(v[1] & 0xffffu)) * A + Bc;
        o0.w = bf2f((unsigned short)(v[1] >> 16))     * A + Bc;
        o1.x = bf2f((unsigned short)(v[2] & 0xffffu)) * A + Bc;
        o1.y = bf2f((unsigned short)(v[2] >> 16))     * A + Bc;
        o1.z = bf2f((unsigned short)(v[3] & 0xffffu)) * A + Bc;
        o1.w = bf2f((unsigned short)(v[3] >> 16))     * A + Bc;
        ((float4*)y)[2 * i]     = o0;
        ((float4*)y)[2 * i + 1] = o1;
    }
}

// ---------------------------------------------------------------- launcher
extern "C" void kernel_launch(void* const* d_in, const int* in_sizes, int n_in,
                              void* d_out, int out_size, void* d_ws, size_t ws_size,
                              hipStream_t stream)
{
    (void)in_sizes; (void)n_in; (void)out_size; (void)ws_size;
    const float* x     = (const float*)d_in[0];
    const float* w_qkv = (const float*)d_in[1];
    const float* w_out = (const float*)d_in[2];
    const float* b_out = (const float*)d_in[3];
    const float* gn_w  = (const float*)d_in[4];
    const float* gn_b  = (const float*)d_in[5];
    float* out = (float*)d_out;

    char* ws = (char*)d_ws;
    unsigned short* q_ws = (unsigned short*)(ws);              // 67,108,864 B (q, then y_bf)
    unsigned short* wq   = (unsigned short*)(ws + 67108864);   //    393,216 B
    unsigned short* W2   = (unsigned short*)(ws + 67502080);   //  1,048,576 B
    float* ctx   = (float*)(ws + 68550656);                    //    262,144 B
    float* Zs    = (float*)(ws + 68812800);                    //      8,192 B
    float* stats = (float*)(ws + 68820992);                    //         64 B
    float* sc    = (float*)(ws + 68821056);                    //         64 B

    k_init <<<dim3(256),                    dim3(256), 0, stream>>>(w_qkv, wq, ctx, Zs, stats);
    k_qkv  <<<dim3(NL / (64 * CHUNKS), NB), dim3(512), 0, stream>>>(x, wq, q_ws, ctx, Zs);
    k_w2   <<<dim3(NC, NB),                 dim3(256), 0, stream>>>(w_out, ctx, Zs, W2);
    k_out  <<<dim3(NL / 128, NB),           dim3(512), 0, stream>>>(q_ws, W2, b_out, stats);
    k_stats<<<dim3(1),                      dim3(64),  0, stream>>>(stats, sc);
    k_norm <<<dim3(2048),                   dim3(256), 0, stream>>>(q_ws, out, sc, gn_w, gn_b);
}